// Round 9
// baseline (26.221 us; speedup 1.0000x reference)
//
#include <hip/hip_runtime.h>
#include <hip/hip_bf16.h>
#include <math.h>

#define IMG 224
#define NLIB 1000
#define ZD 512
#define MAXK 8
#define NTHR 512
#define KA_BLK 125
#define KB_BLK 196
// s buffers: parts of 32 channels, FULL sums per word (written once, >=0)
#define S0F (2 * MAXK * 3136)
#define S1F (4 * MAXK * 784)
#define S2F (8 * MAXK * 196)
#define SFLOATS (S0F + S1F + S2F)   // 87808

__device__ __forceinline__ int clampk(int k) {
    if (k < 1) k = 1;
    if (k > MAXK) k = MAXK;
    return k;
}

// IF-coherent relaxed atomics (bypass non-coherent per-XCD L2) — R6/R8-validated
__device__ __forceinline__ void cgs_f32(float* p, float v) {
    __hip_atomic_store(p, v, __ATOMIC_RELAXED, __HIP_MEMORY_SCOPE_AGENT);
}
__device__ __forceinline__ float cgl_f32(const float* p) {
    return __hip_atomic_load((float*)p, __ATOMIC_RELAXED, __HIP_MEMORY_SCOPE_AGENT);
}

// ---- KA: dists (plain, read next dispatch) + sentinel fill of s (-1.0, sc1) ----
__global__ void __launch_bounds__(NTHR) k_pre(const float* __restrict__ z,
                                              const float* __restrict__ zlib,
                                              float* __restrict__ dists,
                                              float* __restrict__ sfill) {
    int tid = threadIdx.x, lane = tid & 63, wave = tid >> 6, bid = blockIdx.x;

    for (int g = bid * NTHR + tid; g < SFLOATS; g += KA_BLK * NTHR)
        cgs_f32(sfill + g, -1.0f);

    int gw = bid * 8 + wave;                    // 125*8 = 1000 exactly
    const float4* row4 = (const float4*)(zlib + (size_t)gw * ZD);
    const float4* z4   = (const float4*)z;
    float4 a0 = row4[lane],      b0 = z4[lane];
    float4 a1 = row4[64 + lane], b1 = z4[64 + lane];
    float acc = 0.f, d;
    d = a0.x - b0.x; acc += d * d;  d = a0.y - b0.y; acc += d * d;
    d = a0.z - b0.z; acc += d * d;  d = a0.w - b0.w; acc += d * d;
    d = a1.x - b1.x; acc += d * d;  d = a1.y - b1.y; acc += d * d;
    d = a1.z - b1.z; acc += d * d;  d = a1.w - b1.w; acc += d * d;
#pragma unroll
    for (int off = 32; off > 0; off >>= 1) acc += __shfl_xor(acc, off, 64);
    if (lane == 0) dists[gw] = sqrtf(acc);
}

// ---- sentinel poll: one sweep issues ALL K*P loads (one latency round) ----
template<int K, int P>
__device__ float poll_min(const float* base, int strideK, int strideP, int pix) {
    float v[K][P];
    long guard = 0;
    for (;;) {
        bool ok = true;
#pragma unroll
        for (int kq = 0; kq < K; ++kq)
#pragma unroll
            for (int pp = 0; pp < P; ++pp)
                v[kq][pp] = cgl_f32(base + (size_t)pp * strideP + kq * strideK + pix);
#pragma unroll
        for (int kq = 0; kq < K; ++kq)
#pragma unroll
            for (int pp = 0; pp < P; ++pp)
                ok &= (v[kq][pp] >= 0.f);
        if (ok) break;
        if (++guard > 20000000L) break;         // bail -> NaN downstream, visible
        __builtin_amdgcn_s_sleep(1);
    }
    float m = 3.4e38f;
#pragma unroll
    for (int kq = 0; kq < K; ++kq) {
        float s = 0.f;
#pragma unroll
        for (int pp = 0; pp < P; ++pp) s += v[kq][pp];
        m = fminf(m, s);
    }
    return m;
}

template<int P>
__device__ __forceinline__ float poll_min_k(int k, const float* base, int sK, int sP, int pix) {
    switch (k) {
        case 1: return poll_min<1, P>(base, sK, sP, pix);
        case 2: return poll_min<2, P>(base, sK, sP, pix);
        case 3: return poll_min<3, P>(base, sK, sP, pix);
        case 4: return poll_min<4, P>(base, sK, sP, pix);
        case 5: return poll_min<5, P>(base, sK, sP, pix);
        case 6: return poll_min<6, P>(base, sK, sP, pix);
        case 7: return poll_min<7, P>(base, sK, sP, pix);
        default: return poll_min<8, P>(base, sK, sP, pix);
    }
}

// bilinear sample from an LDS window (already min-over-k + sqrt)
__device__ __forceinline__ float bilin(const float* __restrict__ msm, int Wl, int Win,
                                       int bx, int by, float scl, int gx, int gy) {
    float sxf = ((float)gx + 0.5f) * scl - 0.5f;
    float syf = ((float)gy + 0.5f) * scl - 0.5f;
    float fx = floorf(sxf), fy = floorf(syf);
    float wx = sxf - fx,    wy = syf - fy;
    int ix = (int)fx, iy = (int)fy;
    int x0c = min(max(ix, 0), Win - 1) - bx, x1c = min(max(ix + 1, 0), Win - 1) - bx;
    int y0c = min(max(iy, 0), Win - 1) - by, y1c = min(max(iy + 1, 0), Win - 1) - by;
    float v00 = msm[y0c * Wl + x0c], v10 = msm[y0c * Wl + x1c];
    float v01 = msm[y1c * Wl + x0c], v11 = msm[y1c * Wl + x1c];
    return (1.f - wy) * ((1.f - wx) * v00 + wx * v10) +
           wy * ((1.f - wx) * v01 + wx * v11);
}

// ---- KB: gather (waves 0-1, own reg-topk) || staging via sentinel poll
//      (waves 2-4) -> upsample+blur. ZERO barriers. ----
__global__ void __launch_bounds__(NTHR) k_main(
        const float* __restrict__ f0, const float* __restrict__ f1,
        const float* __restrict__ f2,
        const float* __restrict__ l0, const float* __restrict__ l1,
        const float* __restrict__ l2,
        const float* __restrict__ dists, const int* __restrict__ kp,
        float* __restrict__ out,
        float* __restrict__ s0, float* __restrict__ s1, float* __restrict__ s2) {

    __shared__ float msm0[100], msm1[36], msm2[9];
    __shared__ float pre[32 * 32];
    __shared__ float mid[32 * 16];
    __shared__ float wk[17];

    int tid = threadIdx.x, lane = tid & 63, wv = tid >> 6, bid = blockIdx.x;
    int k = clampk(*kp);

    if (tid < 17) {
        float r = (float)(tid - 8) * 0.25f;     // t/sigma, sigma=4
        wk[tid] = expf(-0.5f * r * r);
    }

    int tx = bid % 14, ty = bid / 14;
    int x0 = tx * 16, y0 = ty * 16;
    int b0x = x0 / 4 - 3,  b0y = y0 / 4 - 3;
    int b1x = x0 / 8 - 2,  b1y = y0 / 8 - 2;
    int b2x = x0 / 16 - 1, b2y = y0 / 16 - 1;

    // ---- producers: waves 0-1, block-major spread wave-units ----
    int n0 = k * 1568, n1 = k * 784, n2 = k * 392;
    int njobs = n0 + n1 + n2;                   // k*2744, k=8 -> 343 units
    int nwj = (njobs + 63) >> 6;
    if (wv < 2) {
        int s = bid + KB_BLK * wv;
        bool havejob = (s < nwj);
        bool scorer = (bid == 0 && wv == 0);
        if (havejob || scorer) {
            // per-wave reg top-k (deterministic tie-break)
            float vals[16];
#pragma unroll
            for (int q = 0; q < 16; ++q) {
                int e = lane + 64 * q;
                vals[q] = (e < NLIB) ? dists[e] : 3.4e38f;
            }
            int idxr[8];
            float ssum = 0.f;
#pragma unroll
            for (int it = 0; it < 8; ++it) {
                if (it < k) {
                    float bv = 3.4e38f; int bi = 0x7fffffff;
#pragma unroll
                    for (int q = 0; q < 16; ++q) {
                        if (vals[q] < bv) { bv = vals[q]; bi = lane + 64 * q; }
                    }
#pragma unroll
                    for (int off = 1; off < 64; off <<= 1) {
                        float ov = __shfl_xor(bv, off, 64);
                        int   oi = __shfl_xor(bi, off, 64);
                        if (ov < bv || (ov == bv && oi < bi)) { bv = ov; bi = oi; }
                    }
#pragma unroll
                    for (int q = 0; q < 16; ++q) {
                        if (lane + 64 * q == bi) vals[q] = 3.4e38f;
                    }
                    idxr[it] = bi; ssum += bv;
                } else idxr[it] = 0;
            }
            if (scorer && lane == 0) out[0] = ssum / (float)k;

            if (havejob) {
                int j = s * 64 + lane;
                if (j < njobs) {
                    const float* fmp; const float* lbp; float* op;
                    int kk, pq, cbase, HW, Cfull;
                    if (j < n0) {
                        int r = j;           kk = r / 1568; int q = r % 1568;
                        int part = q / 784;  pq = q % 784;  cbase = part * 32;
                        HW = 3136; Cfull = 64;  fmp = f0; lbp = l0;
                        op = s0 + part * (MAXK * 3136) + kk * 3136;
                    } else if (j < n0 + n1) {
                        int r = j - n0;      kk = r / 784;  int q = r % 784;
                        int part = q / 196;  pq = q % 196;  cbase = part * 32;
                        HW = 784;  Cfull = 128; fmp = f1; lbp = l1;
                        op = s1 + part * (MAXK * 784) + kk * 784;
                    } else {
                        int r = j - n0 - n1; kk = r / 392;  int q = r % 392;
                        int part = q / 49;   pq = q % 49;   cbase = part * 32;
                        HW = 196;  Cfull = 256; fmp = f2; lbp = l2;
                        op = s2 + part * (MAXK * 196) + kk * 196;
                    }
                    int myidx = 0;
#pragma unroll
                    for (int it = 0; it < 8; ++it) if (it == kk) myidx = idxr[it];

                    const float4* lb4 = (const float4*)(lbp + (size_t)myidx * (size_t)Cfull * HW
                                                            + (size_t)cbase * HW);
                    const float4* fb4 = (const float4*)(fmp + (size_t)cbase * HW);
                    int HW4 = HW >> 2;
                    float ax = 0.f, ay = 0.f, az = 0.f, aw = 0.f;
#pragma unroll
                    for (int c = 0; c < 32; ++c) {
                        float4 a = lb4[c * HW4 + pq];
                        float4 b = fb4[c * HW4 + pq];
                        float dx = a.x - b.x, dy = a.y - b.y, dz = a.z - b.z, dw = a.w - b.w;
                        ax += dx * dx; ay += dy * dy; az += dz * dz; aw += dw * dw;
                    }
                    float* o = op + 4 * pq;     // complete 32-ch sums, >= 0
                    cgs_f32(o + 0, ax); cgs_f32(o + 1, ay);
                    cgs_f32(o + 2, az); cgs_f32(o + 3, aw);
                }
            }
        }
    }

    // ---- consumers: waves 2-4 (disjoint from producers), sentinel poll ----
    if (tid >= 128 && tid < 128 + 145) {
        int i = tid - 128;
        float m;
        if (i < 100) {
            int ly = i / 10, lx = i % 10;
            int gx = min(max(b0x + lx, 0), 55), gy = min(max(b0y + ly, 0), 55);
            m = poll_min_k<2>(k, s0, 3136, MAXK * 3136, gy * 56 + gx);
            msm0[i] = sqrtf(m);
        } else if (i < 136) {
            int r = i - 100; int ly = r / 6, lx = r % 6;
            int gx = min(max(b1x + lx, 0), 27), gy = min(max(b1y + ly, 0), 27);
            m = poll_min_k<4>(k, s1, 784, MAXK * 784, gy * 28 + gx);
            msm1[r] = sqrtf(m);
        } else {
            int r = i - 136; int ly = r / 3, lx = r % 3;
            int gx = min(max(b2x + lx, 0), 13), gy = min(max(b2y + ly, 0), 13);
            m = poll_min_k<8>(k, s2, 196, MAXK * 196, gy * 14 + gx);
            msm2[r] = sqrtf(m);
        }
    }
    __syncthreads();

    float wsum = 0.f;
#pragma unroll
    for (int t = 0; t < 17; ++t) wsum += wk[t];
    float inv2 = 1.f / (wsum * wsum);

    // upsample + sum of 3 scales into 32x32 halo tile (zero outside image)
    for (int i = tid; i < 32 * 32; i += NTHR) {
        int lx = i % 32, ly = i / 32;
        int gx = x0 - 8 + lx, gy = y0 - 8 + ly;
        float v = 0.f;
        if ((unsigned)gx < (unsigned)IMG && (unsigned)gy < (unsigned)IMG) {
            v = bilin(msm0, 10, 56, b0x, b0y, 0.25f,   gx, gy)
              + bilin(msm1, 6,  28, b1x, b1y, 0.125f,  gx, gy)
              + bilin(msm2, 3,  14, b2x, b2y, 0.0625f, gx, gy);
        }
        pre[i] = v;
    }
    __syncthreads();

    if (tid < 32 * 16) {
        int cx = tid % 16, ly = tid / 16;
        float acc = 0.f;
#pragma unroll
        for (int t = 0; t < 17; ++t) acc += wk[t] * pre[ly * 32 + cx + t];
        mid[ly * 16 + cx] = acc;
    }
    __syncthreads();

    if (tid < 16 * 16) {
        int ox = tid % 16, oy = tid / 16;
        float acc = 0.f;
#pragma unroll
        for (int t = 0; t < 17; ++t) acc += wk[t] * mid[(oy + t) * 16 + ox];
        out[1 + (y0 + oy) * IMG + (x0 + ox)] = acc * inv2;
    }
}

extern "C" void kernel_launch(void* const* d_in, const int* in_sizes, int n_in,
                              void* d_out, int out_size, void* d_ws, size_t ws_size,
                              hipStream_t stream) {
    const float* z    = (const float*)d_in[0];
    const float* f0   = (const float*)d_in[1];
    const float* f1   = (const float*)d_in[2];
    const float* f2   = (const float*)d_in[3];
    const float* zlib = (const float*)d_in[4];
    const float* l0   = (const float*)d_in[5];
    const float* l1   = (const float*)d_in[6];
    const float* l2   = (const float*)d_in[7];
    const int*   kp   = (const int*)d_in[8];
    float* out = (float*)d_out;

    float* ws    = (float*)d_ws;
    float* dists = ws;                          // 1000
    float* s0    = ws + 1024;                   // 2*MAXK*3136
    float* s1    = s0 + S0F;                    // 4*MAXK*784
    float* s2    = s1 + S1F;                    // 8*MAXK*196

    k_pre<<<KA_BLK, NTHR, 0, stream>>>(z, zlib, dists, s0);
    k_main<<<KB_BLK, NTHR, 0, stream>>>(f0, f1, f2, l0, l1, l2, dists, kp, out,
                                        s0, s1, s2);
}

// Round 10
// 24.126 us; speedup vs baseline: 1.0868x; 1.0868x over previous
//
#include <hip/hip_runtime.h>
#include <hip/hip_bf16.h>
#include <math.h>

#define IMG 224
#define NLIB 1000
#define ZD 512
#define MAXK 8
#define NTHR 512
#define KA_BLK 125
#define KB_BLK 196
#define MTAG 0x5EEDF00Du
// s buffers: parts of 32 channels, FULL sums per word (written once, >= 0)
#define S0F (2 * MAXK * 3136)
#define S1F (4 * MAXK * 784)
#define S2F (8 * MAXK * 196)
#define SFLOATS (S0F + S1F + S2F)   // 87808

__device__ __forceinline__ int clampk(int k) {
    if (k < 1) k = 1;
    if (k > MAXK) k = MAXK;
    return k;
}

// IF-coherent relaxed atomics (bypass non-coherent per-XCD L2) — R6/R8/R9-validated
__device__ __forceinline__ void cgs_u32(unsigned* p, unsigned v) {
    __hip_atomic_store(p, v, __ATOMIC_RELAXED, __HIP_MEMORY_SCOPE_AGENT);
}
__device__ __forceinline__ unsigned cgl_u32(unsigned* p) {
    return __hip_atomic_load(p, __ATOMIC_RELAXED, __HIP_MEMORY_SCOPE_AGENT);
}
__device__ __forceinline__ void cgs_f32(float* p, float v) {
    __hip_atomic_store(p, v, __ATOMIC_RELAXED, __HIP_MEMORY_SCOPE_AGENT);
}
__device__ __forceinline__ float cgl_f32(const float* p) {
    return __hip_atomic_load((float*)p, __ATOMIC_RELAXED, __HIP_MEMORY_SCOPE_AGENT);
}

// ---- KA: sentinel fill + dists + internal light barrier + single-wave topk ----
__global__ void __launch_bounds__(NTHR) k_pre(
        const float* __restrict__ z, const float* __restrict__ zlib,
        const int* __restrict__ kp,
        float* __restrict__ dists, unsigned* __restrict__ d1,
        int* __restrict__ idxs, float* __restrict__ out,
        float* __restrict__ sfill) {
    int tid = threadIdx.x, lane = tid & 63, wave = tid >> 6, bid = blockIdx.x;
    int k = clampk(*kp);

    // sentinel -1 prefill of s buffers (overwrites previous replay's >=0 values;
    // KB is ordered after by the dispatch boundary)
    for (int g = bid * NTHR + tid; g < SFLOATS; g += KA_BLK * NTHR)
        cgs_f32(sfill + g, -1.0f);

    // dists: one wave per entry, 125*8 = 1000 exactly
    int gw = bid * 8 + wave;
    {
        const float4* row4 = (const float4*)(zlib + (size_t)gw * ZD);
        const float4* z4   = (const float4*)z;
        float4 a0 = row4[lane],      b0 = z4[lane];
        float4 a1 = row4[64 + lane], b1 = z4[64 + lane];
        float acc = 0.f, d;
        d = a0.x - b0.x; acc += d * d;  d = a0.y - b0.y; acc += d * d;
        d = a0.z - b0.z; acc += d * d;  d = a0.w - b0.w; acc += d * d;
        d = a1.x - b1.x; acc += d * d;  d = a1.y - b1.y; acc += d * d;
        d = a1.z - b1.z; acc += d * d;  d = a1.w - b1.w; acc += d * d;
#pragma unroll
        for (int off = 32; off > 0; off >>= 1) acc += __shfl_xor(acc, off, 64);
        if (lane == 0) cgs_f32(&dists[gw], sqrtf(acc));
    }
    __syncthreads();                            // drains this block's sc1 stores
    if (tid == 0) cgs_u32(d1 + bid, MTAG);
    if (bid != 0 || wave != 0) return;

    // block 0 wave 0: poll all 125 arrival slots (2 per lane)
    {
        unsigned pend = 0;
#pragma unroll
        for (int q = 0; q < 2; ++q) { int i = q * 64 + lane; if (i < KA_BLK) pend |= 1u << q; }
        long guard = 0;
        for (;;) {
#pragma unroll
            for (int q = 0; q < 2; ++q) {
                int i = q * 64 + lane;
                if ((pend & (1u << q)) && cgl_u32(d1 + i) == MTAG) pend &= ~(1u << q);
            }
            if (__all(pend == 0)) break;
            if (++guard > 100000000L) break;
            __builtin_amdgcn_s_sleep(2);
        }
    }
    asm volatile("" ::: "memory");

    // top-k in registers (single wave), deterministic tie-break
    float vals[16];
#pragma unroll
    for (int q = 0; q < 16; ++q) {
        int e = lane + 64 * q;
        vals[q] = (e < NLIB) ? cgl_f32(&dists[e]) : 3.4e38f;
    }
    float ssum = 0.f;
    for (int it = 0; it < k; ++it) {
        float bv = 3.4e38f; int bi = 0x7fffffff;
#pragma unroll
        for (int q = 0; q < 16; ++q) {
            if (vals[q] < bv) { bv = vals[q]; bi = lane + 64 * q; }
        }
#pragma unroll
        for (int off = 1; off < 64; off <<= 1) {
            float ov = __shfl_xor(bv, off, 64);
            int   oi = __shfl_xor(bi, off, 64);
            if (ov < bv || (ov == bv && oi < bi)) { bv = ov; bi = oi; }
        }
#pragma unroll
        for (int q = 0; q < 16; ++q) {
            if (lane + 64 * q == bi) vals[q] = 3.4e38f;
        }
        if (lane == 0) idxs[it] = bi;           // plain store; KB reads across dispatch
        ssum += bv;
    }
    if (lane == 0) out[0] = ssum / (float)k;

    // reset arrival slots for next replay (only this wave ever reads them)
#pragma unroll
    for (int q = 0; q < 2; ++q) { int i = q * 64 + lane; if (i < KA_BLK) cgs_u32(d1 + i, 0u); }
}

// ---- sentinel poll: one sweep issues ALL K*P loads (one latency round) ----
template<int K, int P>
__device__ float poll_min(const float* base, int strideK, int strideP, int pix) {
    float v[K][P];
    long guard = 0;
    for (;;) {
        bool ok = true;
#pragma unroll
        for (int kq = 0; kq < K; ++kq)
#pragma unroll
            for (int pp = 0; pp < P; ++pp)
                v[kq][pp] = cgl_f32(base + (size_t)pp * strideP + kq * strideK + pix);
#pragma unroll
        for (int kq = 0; kq < K; ++kq)
#pragma unroll
            for (int pp = 0; pp < P; ++pp)
                ok &= (v[kq][pp] >= 0.f);
        if (ok) break;
        if (++guard > 20000000L) break;         // bail -> visible wrong result, no hang
        __builtin_amdgcn_s_sleep(1);
    }
    float m = 3.4e38f;
#pragma unroll
    for (int kq = 0; kq < K; ++kq) {
        float s = 0.f;
#pragma unroll
        for (int pp = 0; pp < P; ++pp) s += v[kq][pp];
        m = fminf(m, s);
    }
    return m;
}

template<int P>
__device__ __forceinline__ float poll_min_k(int k, const float* base, int sK, int sP, int pix) {
    switch (k) {
        case 1: return poll_min<1, P>(base, sK, sP, pix);
        case 2: return poll_min<2, P>(base, sK, sP, pix);
        case 3: return poll_min<3, P>(base, sK, sP, pix);
        case 4: return poll_min<4, P>(base, sK, sP, pix);
        case 5: return poll_min<5, P>(base, sK, sP, pix);
        case 6: return poll_min<6, P>(base, sK, sP, pix);
        case 7: return poll_min<7, P>(base, sK, sP, pix);
        default: return poll_min<8, P>(base, sK, sP, pix);
    }
}

// bilinear sample from an LDS window (already min-over-k + sqrt)
__device__ __forceinline__ float bilin(const float* __restrict__ msm, int Wl, int Win,
                                       int bx, int by, float scl, int gx, int gy) {
    float sxf = ((float)gx + 0.5f) * scl - 0.5f;
    float syf = ((float)gy + 0.5f) * scl - 0.5f;
    float fx = floorf(sxf), fy = floorf(syf);
    float wx = sxf - fx,    wy = syf - fy;
    int ix = (int)fx, iy = (int)fy;
    int x0c = min(max(ix, 0), Win - 1) - bx, x1c = min(max(ix + 1, 0), Win - 1) - bx;
    int y0c = min(max(iy, 0), Win - 1) - by, y1c = min(max(iy + 1, 0), Win - 1) - by;
    float v00 = msm[y0c * Wl + x0c], v10 = msm[y0c * Wl + x1c];
    float v01 = msm[y1c * Wl + x0c], v11 = msm[y1c * Wl + x1c];
    return (1.f - wy) * ((1.f - wx) * v00 + wx * v10) +
           wy * ((1.f - wx) * v01 + wx * v11);
}

// ---- KB: producers (waves 0-1, idxs from KA, gather immediately)
//      || consumers (waves 2-4, sentinel poll) -> upsample+blur. ZERO barriers. ----
__global__ void __launch_bounds__(NTHR) k_main(
        const float* __restrict__ f0, const float* __restrict__ f1,
        const float* __restrict__ f2,
        const float* __restrict__ l0, const float* __restrict__ l1,
        const float* __restrict__ l2,
        const int* __restrict__ idxs, const int* __restrict__ kp,
        float* __restrict__ out,
        float* __restrict__ s0, float* __restrict__ s1, float* __restrict__ s2) {

    __shared__ float msm0[100], msm1[36], msm2[9];
    __shared__ float pre[32 * 32];
    __shared__ float mid[32 * 16];
    __shared__ float wk[17];

    int tid = threadIdx.x, lane = tid & 63, wv = tid >> 6, bid = blockIdx.x;
    int k = clampk(*kp);

    if (tid < 17) {
        float r = (float)(tid - 8) * 0.25f;     // t/sigma, sigma=4
        wk[tid] = expf(-0.5f * r * r);
    }

    int tx = bid % 14, ty = bid / 14;
    int x0 = tx * 16, y0 = ty * 16;
    int b0x = x0 / 4 - 3,  b0y = y0 / 4 - 3;
    int b1x = x0 / 8 - 2,  b1y = y0 / 8 - 2;
    int b2x = x0 / 16 - 1, b2y = y0 / 16 - 1;

    // ---- producers: waves 0-1, block-major spread wave-units ----
    int n0 = k * 1568, n1 = k * 784, n2 = k * 392;
    int njobs = n0 + n1 + n2;                   // k*2744
    int nwj = (njobs + 63) >> 6;
    if (wv < 2) {
        int s = bid + KB_BLK * wv;
        if (s < nwj) {
            int j = s * 64 + lane;
            if (j < njobs) {
                const float* fmp; const float* lbp; float* op;
                int kk, pq, cbase, HW, Cfull;
                if (j < n0) {
                    int r = j;           kk = r / 1568; int q = r % 1568;
                    int part = q / 784;  pq = q % 784;  cbase = part * 32;
                    HW = 3136; Cfull = 64;  fmp = f0; lbp = l0;
                    op = s0 + part * (MAXK * 3136) + kk * 3136;
                } else if (j < n0 + n1) {
                    int r = j - n0;      kk = r / 784;  int q = r % 784;
                    int part = q / 196;  pq = q % 196;  cbase = part * 32;
                    HW = 784;  Cfull = 128; fmp = f1; lbp = l1;
                    op = s1 + part * (MAXK * 784) + kk * 784;
                } else {
                    int r = j - n0 - n1; kk = r / 392;  int q = r % 392;
                    int part = q / 49;   pq = q % 49;   cbase = part * 32;
                    HW = 196;  Cfull = 256; fmp = f2; lbp = l2;
                    op = s2 + part * (MAXK * 196) + kk * 196;
                }
                int myidx = idxs[kk];           // plain read; coherent across dispatch
                const float4* lb4 = (const float4*)(lbp + (size_t)myidx * (size_t)Cfull * HW
                                                        + (size_t)cbase * HW);
                const float4* fb4 = (const float4*)(fmp + (size_t)cbase * HW);
                int HW4 = HW >> 2;
                float ax = 0.f, ay = 0.f, az = 0.f, aw = 0.f;
#pragma unroll
                for (int c = 0; c < 32; ++c) {
                    float4 a = lb4[c * HW4 + pq];
                    float4 b = fb4[c * HW4 + pq];
                    float dx = a.x - b.x, dy = a.y - b.y, dz = a.z - b.z, dw = a.w - b.w;
                    ax += dx * dx; ay += dy * dy; az += dz * dz; aw += dw * dw;
                }
                float* o = op + 4 * pq;         // complete 32-ch sums, >= 0
                cgs_f32(o + 0, ax); cgs_f32(o + 1, ay);
                cgs_f32(o + 2, az); cgs_f32(o + 3, aw);
            }
        }
    }

    // ---- consumers: waves 2-4 (disjoint from producers), sentinel poll ----
    if (tid >= 128 && tid < 128 + 145) {
        int i = tid - 128;
        float m;
        if (i < 100) {
            int ly = i / 10, lx = i % 10;
            int gx = min(max(b0x + lx, 0), 55), gy = min(max(b0y + ly, 0), 55);
            m = poll_min_k<2>(k, s0, 3136, MAXK * 3136, gy * 56 + gx);
            msm0[i] = sqrtf(m);
        } else if (i < 136) {
            int r = i - 100; int ly = r / 6, lx = r % 6;
            int gx = min(max(b1x + lx, 0), 27), gy = min(max(b1y + ly, 0), 27);
            m = poll_min_k<4>(k, s1, 784, MAXK * 784, gy * 28 + gx);
            msm1[r] = sqrtf(m);
        } else {
            int r = i - 136; int ly = r / 3, lx = r % 3;
            int gx = min(max(b2x + lx, 0), 13), gy = min(max(b2y + ly, 0), 13);
            m = poll_min_k<8>(k, s2, 196, MAXK * 196, gy * 14 + gx);
            msm2[r] = sqrtf(m);
        }
    }
    __syncthreads();

    float wsum = 0.f;
#pragma unroll
    for (int t = 0; t < 17; ++t) wsum += wk[t];
    float inv2 = 1.f / (wsum * wsum);

    // upsample + sum of 3 scales into 32x32 halo tile (zero outside image)
    for (int i = tid; i < 32 * 32; i += NTHR) {
        int lx = i % 32, ly = i / 32;
        int gx = x0 - 8 + lx, gy = y0 - 8 + ly;
        float v = 0.f;
        if ((unsigned)gx < (unsigned)IMG && (unsigned)gy < (unsigned)IMG) {
            v = bilin(msm0, 10, 56, b0x, b0y, 0.25f,   gx, gy)
              + bilin(msm1, 6,  28, b1x, b1y, 0.125f,  gx, gy)
              + bilin(msm2, 3,  14, b2x, b2y, 0.0625f, gx, gy);
        }
        pre[i] = v;
    }
    __syncthreads();

    // horizontal blur: 32 rows x 16 center cols
    if (tid < 32 * 16) {
        int cx = tid % 16, ly = tid / 16;
        float acc = 0.f;
#pragma unroll
        for (int t = 0; t < 17; ++t) acc += wk[t] * pre[ly * 32 + cx + t];
        mid[ly * 16 + cx] = acc;
    }
    __syncthreads();

    // vertical blur + store
    if (tid < 16 * 16) {
        int ox = tid % 16, oy = tid / 16;
        float acc = 0.f;
#pragma unroll
        for (int t = 0; t < 17; ++t) acc += wk[t] * mid[(oy + t) * 16 + ox];
        out[1 + (y0 + oy) * IMG + (x0 + ox)] = acc * inv2;
    }
}

extern "C" void kernel_launch(void* const* d_in, const int* in_sizes, int n_in,
                              void* d_out, int out_size, void* d_ws, size_t ws_size,
                              hipStream_t stream) {
    const float* z    = (const float*)d_in[0];
    const float* f0   = (const float*)d_in[1];
    const float* f1   = (const float*)d_in[2];
    const float* f2   = (const float*)d_in[3];
    const float* zlib = (const float*)d_in[4];
    const float* l0   = (const float*)d_in[5];
    const float* l1   = (const float*)d_in[6];
    const float* l2   = (const float*)d_in[7];
    const int*   kp   = (const int*)d_in[8];
    float* out = (float*)d_out;

    float*    ws    = (float*)d_ws;
    float*    dists = ws;                       // 1000 (sc1)
    unsigned* d1    = (unsigned*)(ws + 1000);   // 125 arrival slots
    int*      idxs  = (int*)(ws + 1152);        // 8 (plain)
    float*    s0    = ws + 1664;                // 2*MAXK*3136
    float*    s1    = s0 + S0F;                 // 4*MAXK*784
    float*    s2    = s1 + S1F;                 // 8*MAXK*196

    k_pre<<<KA_BLK, NTHR, 0, stream>>>(z, zlib, kp, dists, d1, idxs, out, s0);
    k_main<<<KB_BLK, NTHR, 0, stream>>>(f0, f1, f2, l0, l1, l2, idxs, kp, out,
                                        s0, s1, s2);
}